// Round 6
// baseline (26332.785 us; speedup 1.0000x reference)
//
#include <hip/hip_runtime.h>
#include <hip/hip_bf16.h>
#include <math.h>

#define BB 1024
#define TT 13
#define YY 188
#define HH 512
#define GG 1536
#define YP 192
#define DS 13

typedef float f4 __attribute__((ext_vector_type(4)));
typedef float f2 __attribute__((ext_vector_type(2)));

__device__ __forceinline__ float sigf(float x) { return 1.f / (1.f + expf(-x)); }

// Stage W_ih0 (GG x 188) into fp32 (GG x 192), zero-padding K. (Only weight
// whose K isn't already a multiple of 32; all others are used in-place.)
__global__ void k_stage_w(const float* __restrict__ src, float* __restrict__ dst,
                          int N, int Ksrc, int Kpad) {
  int idx = blockIdx.x * 256 + threadIdx.x;
  if (idx >= N * Kpad) return;
  int n = idx / Kpad, k = idx % Kpad;
  dst[idx] = (k < Ksrc) ? src[(size_t)n * Ksrc + k] : 0.f;
}

// Setup: t-major fp32 padded token buffer (13,B,192), zeroed y-token slots,
// fp32 residual seeded with x[:,12,:].
__global__ void k_setup_x(const float* __restrict__ x, float* __restrict__ xpad,
                          float* __restrict__ ypad, float* __restrict__ res) {
  int idx = blockIdx.x * 256 + threadIdx.x;
  const int total = TT * BB * YP;
  if (idx < total) {
    int k = idx % YP;
    int b = (idx / YP) % BB;
    int t = idx / (YP * BB);
    float v = 0.f;
    if (k < YY) v = x[((size_t)b * TT + t) * YY + k];
    xpad[idx] = v;
    ypad[idx] = 0.f;
  }
  if (idx < BB * YY) {
    int yy = idx % YY;
    int b = idx / YY;
    res[idx] = x[((size_t)b * TT + 12) * YY + yy];
  }
}

// ---------------------------------------------------------------------------
// Fused fp32 GRU step (pure VALU — exact numerics vs the fp32 reference).
//   xg = A1 @ W1^T   (K = KT1*32; r,z accumulated jointly with gh; n apart)
//   gh = A2 @ W2^T   (K = 512)   [skipped when zero_h]
//   r = sig(xr+ghr+bxr+bhr); z = sig(...); n = tanh(xn+bxn + r*(ghn+bhn))
//   h = (1-z)*n + z*h_prev      (h_prev == A2)
// Block: 32 rows x 64 h-cols, 256 threads; thread = 4 rows x 2 cols x 4 accs.
// ---------------------------------------------------------------------------
template <int KT1>
__global__ __launch_bounds__(256) void gru_v(
    const float* __restrict__ A1, int lda1,
    const float* __restrict__ W1,   // [GG][KT1*32] fp32 (padded if needed)
    const float* __restrict__ A2,   // h_prev [BB][HH] fp32
    const float* __restrict__ W2,   // [GG][HH] fp32 (raw W_hh)
    const float* __restrict__ b1,   // fp32 [GG] (raw b_ih)
    const float* __restrict__ b2,   // fp32 [GG] (raw b_hh)
    float* __restrict__ hout,
    int zero_h)
{
  __shared__ float Al[32][36];
  __shared__ float Wl[3][32][66];
  const int tx = threadIdx.x;
  const int c  = tx & 31;          // col pair index: cols c*2, c*2+1
  const int rg = tx >> 5;          // row group: rows rg*4 .. rg*4+3
  const int m0 = blockIdx.x * 32;
  const int c0 = blockIdx.y * 64;

  float ar[4][2] = {}, az[4][2] = {}, axn[4][2] = {}, ahn[4][2] = {};

  const int lr = tx >> 3;          // A-load row (0..31)
  const int lk = (tx & 7) * 4;     // A-load k within tile

  for (int kt = 0; kt < KT1; ++kt) {
    f4 a = *(const f4*)&A1[(size_t)(m0 + lr) * lda1 + kt * 32 + lk];
#pragma unroll
    for (int j = 0; j < 4; ++j) Al[lk + j][lr] = a[j];
#pragma unroll
    for (int g = 0; g < 3; ++g)
#pragma unroll
      for (int it = 0; it < 2; ++it) {
        int flat = it * 256 + tx;
        int nl = flat >> 3, k4 = (flat & 7) * 4;
        f4 wv = *(const f4*)&W1[(size_t)(g * HH + c0 + nl) * (KT1 * 32) + kt * 32 + k4];
#pragma unroll
        for (int j = 0; j < 4; ++j) Wl[g][k4 + j][nl] = wv[j];
      }
    __syncthreads();
#pragma unroll 8
    for (int k = 0; k < 32; ++k) {
      f4 a4 = *(const f4*)&Al[k][rg * 4];
      f2 wr = *(const f2*)&Wl[0][k][c * 2];
      f2 wz = *(const f2*)&Wl[1][k][c * 2];
      f2 wn = *(const f2*)&Wl[2][k][c * 2];
#pragma unroll
      for (int i = 0; i < 4; ++i)
#pragma unroll
        for (int j = 0; j < 2; ++j) {
          ar[i][j]  = fmaf(a4[i], wr[j], ar[i][j]);
          az[i][j]  = fmaf(a4[i], wz[j], az[i][j]);
          axn[i][j] = fmaf(a4[i], wn[j], axn[i][j]);
        }
    }
    __syncthreads();
  }

  if (!zero_h) {
    for (int kt = 0; kt < HH / 32; ++kt) {
      f4 a = *(const f4*)&A2[(size_t)(m0 + lr) * HH + kt * 32 + lk];
#pragma unroll
      for (int j = 0; j < 4; ++j) Al[lk + j][lr] = a[j];
#pragma unroll
      for (int g = 0; g < 3; ++g)
#pragma unroll
        for (int it = 0; it < 2; ++it) {
          int flat = it * 256 + tx;
          int nl = flat >> 3, k4 = (flat & 7) * 4;
          f4 wv = *(const f4*)&W2[(size_t)(g * HH + c0 + nl) * HH + kt * 32 + k4];
#pragma unroll
          for (int j = 0; j < 4; ++j) Wl[g][k4 + j][nl] = wv[j];
        }
      __syncthreads();
#pragma unroll 8
      for (int k = 0; k < 32; ++k) {
        f4 a4 = *(const f4*)&Al[k][rg * 4];
        f2 wr = *(const f2*)&Wl[0][k][c * 2];
        f2 wz = *(const f2*)&Wl[1][k][c * 2];
        f2 wn = *(const f2*)&Wl[2][k][c * 2];
#pragma unroll
        for (int i = 0; i < 4; ++i)
#pragma unroll
          for (int j = 0; j < 2; ++j) {
            ar[i][j]  = fmaf(a4[i], wr[j], ar[i][j]);
            az[i][j]  = fmaf(a4[i], wz[j], az[i][j]);
            ahn[i][j] = fmaf(a4[i], wn[j], ahn[i][j]);
          }
      }
      __syncthreads();
    }
  }

#pragma unroll
  for (int i = 0; i < 4; ++i) {
    const int row = m0 + rg * 4 + i;
#pragma unroll
    for (int j = 0; j < 2; ++j) {
      const int col = c0 + c * 2 + j;
      const float r = sigf(ar[i][j] + b1[col] + b2[col]);
      const float z = sigf(az[i][j] + b1[col + HH] + b2[col + HH]);
      const float n = tanhf(axn[i][j] + b1[col + 2 * HH] + r * (ahn[i][j] + b2[col + 2 * HH]));
      const float hp = zero_h ? 0.f : A2[(size_t)row * HH + col];
      hout[(size_t)row * HH + col] = (1.f - z) * n + z * hp;
    }
  }
}

// ---------------------------------------------------------------------------
// Output projection, last timestep only (fp32 VALU):
// o = relu(h1) @ W_out^T + b_out + res; res <- o; d_out[:,d,:] <- o (FP32 —
// the reference's output dtype; round-5 analysis: d_out is float*).
// y-token slot d <- o (fp32 feedback, matching the reference exactly).
// ---------------------------------------------------------------------------
__global__ __launch_bounds__(256) void out_v(
    const float* __restrict__ h1,
    const float* __restrict__ Wo,   // [YY][HH] fp32 (raw W_out)
    const float* __restrict__ bo,
    float* __restrict__ res,
    float* __restrict__ ytok,
    float* __restrict__ outp,
    int d)
{
  int idx = blockIdx.x * 256 + threadIdx.x;
  if (idx >= BB * YY) return;
  int col = idx % YY, row = idx / YY;
  const float* hr = h1 + (size_t)row * HH;
  const float* wr = Wo + (size_t)col * HH;
  float acc = 0.f;
#pragma unroll 4
  for (int k = 0; k < HH; k += 4) {
    f4 h = *(const f4*)&hr[k];
    f4 w = *(const f4*)&wr[k];
#pragma unroll
    for (int j = 0; j < 4; ++j) acc = fmaf(fmaxf(h[j], 0.f), w[j], acc);
  }
  float o = acc + bo[col] + res[idx];
  res[idx] = o;
  outp[((size_t)row * DS + d) * YY + col] = o;
  ytok[(size_t)row * YP + col] = o;
}

extern "C" void kernel_launch(void* const* d_in, const int* in_sizes, int n_in,
                              void* d_out, int out_size, void* d_ws, size_t ws_size,
                              hipStream_t stream)
{
  // role mapping insurance: match in_sizes against the dict-order signature;
  // fall back to greedy size matching (round-5 sentinel confirmed d_in[0]=x).
  static const int sig_dict[11] = {2501632, 288768, 786432, 1536, 1536,
                                   786432, 786432, 1536, 1536, 96256, 188};
  int map[11];
  bool dict_ok = (n_in == 11);
  if (dict_ok)
    for (int r = 0; r < 11; ++r)
      if (in_sizes[r] != sig_dict[r]) { dict_ok = false; break; }
  if (dict_ok) { for (int r = 0; r < 11; ++r) map[r] = r; }
  else {
    bool used[16] = {};
    for (int r = 0; r < 11; ++r) {
      map[r] = r < n_in ? r : 0;
      for (int i = 0; i < n_in && i < 16; ++i)
        if (!used[i] && in_sizes[i] == sig_dict[r]) { map[r] = i; used[i] = true; break; }
    }
  }
  const float* x     = (const float*)d_in[map[0]];
  const float* W_ih0 = (const float*)d_in[map[1]];
  const float* W_hh0 = (const float*)d_in[map[2]];
  const float* b_ih0 = (const float*)d_in[map[3]];
  const float* b_hh0 = (const float*)d_in[map[4]];
  const float* W_ih1 = (const float*)d_in[map[5]];
  const float* W_hh1 = (const float*)d_in[map[6]];
  const float* b_ih1 = (const float*)d_in[map[7]];
  const float* b_hh1 = (const float*)d_in[map[8]];
  const float* W_out = (const float*)d_in[map[9]];
  const float* b_out = (const float*)d_in[map[10]];
  float* outp = (float*)d_out;

  char* p = (char*)d_ws;
  auto alloc = [&](size_t bytes) { char* q = p; p += (bytes + 255) & ~(size_t)255; return q; };
  float* xpadf = (float*)alloc((size_t)TT * BB * YP * 4);
  float* ypadf = (float*)alloc((size_t)DS * BB * YP * 4);
  float* Wih0p = (float*)alloc((size_t)GG * YP * 4);
  float* h0f[2]; float* h1f[2];
  for (int i = 0; i < 2; ++i) {
    h0f[i] = (float*)alloc((size_t)BB * HH * 4);
    h1f[i] = (float*)alloc((size_t)BB * HH * 4);
  }
  float* res = (float*)alloc((size_t)BB * YY * 4);

  k_setup_x<<<(TT * BB * YP + 255) / 256, 256, 0, stream>>>(x, xpadf, ypadf, res);
  k_stage_w<<<(GG * YP + 255) / 256, 256, 0, stream>>>(W_ih0, Wih0p, GG, YY, YP);

  const dim3 grid(32, 8);
  for (int d = 0; d < DS; ++d) {
    for (int t = 0; t < TT; ++t) {
      // window token t of decode step d: originals d+t, else generated t-13+d
      const float* tok = (t < TT - d) ? (xpadf + (size_t)(d + t) * BB * YP)
                                      : (ypadf + (size_t)(t - TT + d) * BB * YP);
      const int rd = t & 1, wr = (t + 1) & 1;  // ping-pong h buffers
      gru_v<6><<<grid, 256, 0, stream>>>(tok, YP, Wih0p, h0f[rd], W_hh0,
                                         b_ih0, b_hh0, h0f[wr], t == 0);
      gru_v<16><<<grid, 256, 0, stream>>>(h0f[wr], HH, W_ih1, h1f[rd], W_hh1,
                                          b_ih1, b_hh1, h1f[wr], t == 0);
    }
    // after t=12 the live h1 buffer is index (12+1)&1 == 1
    out_v<<<(BB * YY + 255) / 256, 256, 0, stream>>>(h1f[1], W_out, b_out, res,
                                                     ypadf + (size_t)d * BB * YP, outp, d);
  }
}

// Round 7
// 11568.770 us; speedup vs baseline: 2.2762x; 2.2762x over previous
//
#include <hip/hip_runtime.h>
#include <hip/hip_bf16.h>
#include <math.h>

using bf16 = __hip_bfloat16;

#define BB 1024
#define TT 13
#define YY 188
#define HH 512
#define GG 1536
#define YP 192
#define DS 13

typedef __bf16 bf16x8 __attribute__((ext_vector_type(8)));
typedef float f32x4 __attribute__((ext_vector_type(4)));
typedef float f4 __attribute__((ext_vector_type(4)));

__device__ __forceinline__ float sigf(float x) { return 1.f / (1.f + expf(-x)); }
__device__ __forceinline__ bf16x8 ldf(const bf16* p) {
  return *reinterpret_cast<const bf16x8*>(p);
}
__device__ __forceinline__ f32x4 mf(bf16x8 a, bf16x8 b, f32x4 c) {
  return __builtin_amdgcn_mfma_f32_16x16x32_bf16(a, b, c, 0, 0, 0);
}
// split v into hi + lo bf16 (captures ~16 mantissa bits total)
__device__ __forceinline__ void split2(float v, bf16& hi, bf16& lo) {
  hi = __float2bfloat16(v);
  lo = __float2bfloat16(v - __bfloat162float(hi));
}

// ---------------------------------------------------------------------------
// Swizzle a row-major (Nsrc x Ksrc) fp32 weight into MFMA B-fragment order,
// split hi/lo, zero-padded to (Npad x Kpad). Frag lane l of tile (nt,kt)
// holds W[nt*16 + (l&15)][kt*32 + (l>>4)*8 + j], j=0..7 contiguous, so the
// kernel-side B-frag load is one coalesced 1 KiB dwordx4 per wave.
// One thread per (nt,kt,lane); grid covers (Npad/16)*(Kpad/32)*64 threads.
// ---------------------------------------------------------------------------
__global__ void k_swz2(const float* __restrict__ src, bf16* __restrict__ dhi,
                       bf16* __restrict__ dlo, int Nsrc, int Ksrc, int Kpad) {
  int idx = blockIdx.x * 256 + threadIdx.x;
  int ks = Kpad >> 5;
  int l = idx & 63;
  int ntkt = idx >> 6;
  int nt = ntkt / ks, kt = ntkt - nt * ks;
  int n = nt * 16 + (l & 15);
  int k0 = kt * 32 + (l >> 4) * 8;
#pragma unroll
  for (int j = 0; j < 8; ++j) {
    int k = k0 + j;
    float v = (n < Nsrc && k < Ksrc) ? src[(size_t)n * Ksrc + k] : 0.f;
    bf16 h, lo;
    split2(v, h, lo);
    dhi[(size_t)idx * 8 + j] = h;
    dlo[(size_t)idx * 8 + j] = lo;
  }
}

// Setup: t-major hi/lo token buffers (13,B,192), zeroed y-token slots,
// fp32 residual seeded with x[:,12,:].
__global__ void k_setup_x(const float* __restrict__ x, bf16* __restrict__ xh,
                          bf16* __restrict__ xl, bf16* __restrict__ yh,
                          bf16* __restrict__ yl, float* __restrict__ res) {
  int idx = blockIdx.x * 256 + threadIdx.x;
  const int total = TT * BB * YP;
  if (idx < total) {
    int k = idx % YP;
    int b = (idx / YP) % BB;
    int t = idx / (YP * BB);
    float v = 0.f;
    if (k < YY) v = x[((size_t)b * TT + t) * YY + k];
    bf16 h, lo;
    split2(v, h, lo);
    xh[idx] = h; xl[idx] = lo;
    yh[idx] = __float2bfloat16(0.f);
    yl[idx] = __float2bfloat16(0.f);
  }
  if (idx < BB * YY) {
    int yy = idx % YY;
    int b = idx / YY;
    res[idx] = x[((size_t)b * TT + 12) * YY + yy];
  }
}

// ---------------------------------------------------------------------------
// Fused GRU step, split-bf16 MFMA (3-term: AhiWhi + AloWhi + AhiWlo — fp32-
// grade accuracy, ~2^-16 rel):
//   xg = A1 @ W1^T  (K = K1S*32)   gh = A2 @ W2^T  (K = 512, skip if zero_h)
//   r = sig(xgr+ghr+b..); z = sig(..); n = tanh(xgn+bxn + r*(ghn+bhn))
//   h = (1-z)*n + z*h_prev
// Block: 64 rows x 32 h-cols, 4 waves (2x2); wave = 32 rows x 16 cols x 3
// gates. No LDS — B-frags come straight from the pre-swizzled global arrays
// (1 KiB coalesced per load, L2-resident).
// ---------------------------------------------------------------------------
template <int K1S>
__global__ __launch_bounds__(256) void gru_m(
    const bf16* __restrict__ A1h, const bf16* __restrict__ A1l, int lda1,
    const bf16* __restrict__ W1h, const bf16* __restrict__ W1l,
    const float* __restrict__ b1,
    const bf16* __restrict__ A2h, const bf16* __restrict__ A2l,
    const bf16* __restrict__ W2h, const bf16* __restrict__ W2l,
    const float* __restrict__ b2,
    const float* __restrict__ hprev,
    float* __restrict__ hout, bf16* __restrict__ hoh, bf16* __restrict__ hol,
    int zero_h)
{
  const int w  = threadIdx.x >> 6;
  const int l  = threadIdx.x & 63;
  const int lr = l & 15;
  const int lq = l >> 4;
  const int m0 = blockIdx.x * 64 + (w >> 1) * 32;
  const int cw = blockIdx.y * 32 + (w & 1) * 16;
  const int kq = lq * 8;
  const int nt0 = cw >> 4;

  const f32x4 vzero = {0.f, 0.f, 0.f, 0.f};
  f32x4 ax[2][3], ah[2][3];
#pragma unroll
  for (int f = 0; f < 2; ++f)
#pragma unroll
    for (int g = 0; g < 3; ++g) { ax[f][g] = vzero; ah[f][g] = vzero; }

#pragma unroll 2
  for (int kt = 0; kt < K1S; ++kt) {
    bf16x8 a0h = ldf(A1h + (size_t)(m0 + lr) * lda1 + kt * 32 + kq);
    bf16x8 a0l = ldf(A1l + (size_t)(m0 + lr) * lda1 + kt * 32 + kq);
    bf16x8 a1h = ldf(A1h + (size_t)(m0 + 16 + lr) * lda1 + kt * 32 + kq);
    bf16x8 a1l = ldf(A1l + (size_t)(m0 + 16 + lr) * lda1 + kt * 32 + kq);
#pragma unroll
    for (int g = 0; g < 3; ++g) {
      size_t off = ((size_t)((nt0 + g * 32) * K1S + kt) * 64 + l) * 8;
      bf16x8 bh = ldf(W1h + off);
      bf16x8 bl = ldf(W1l + off);
      ax[0][g] = mf(a0h, bl, mf(a0l, bh, mf(a0h, bh, ax[0][g])));
      ax[1][g] = mf(a1h, bl, mf(a1l, bh, mf(a1h, bh, ax[1][g])));
    }
  }
  if (!zero_h) {
#pragma unroll 2
    for (int kt = 0; kt < HH / 32; ++kt) {
      bf16x8 a0h = ldf(A2h + (size_t)(m0 + lr) * HH + kt * 32 + kq);
      bf16x8 a0l = ldf(A2l + (size_t)(m0 + lr) * HH + kt * 32 + kq);
      bf16x8 a1h = ldf(A2h + (size_t)(m0 + 16 + lr) * HH + kt * 32 + kq);
      bf16x8 a1l = ldf(A2l + (size_t)(m0 + 16 + lr) * HH + kt * 32 + kq);
#pragma unroll
      for (int g = 0; g < 3; ++g) {
        size_t off = ((size_t)((nt0 + g * 32) * (HH / 32) + kt) * 64 + l) * 8;
        bf16x8 bh = ldf(W2h + off);
        bf16x8 bl = ldf(W2l + off);
        ah[0][g] = mf(a0h, bl, mf(a0l, bh, mf(a0h, bh, ah[0][g])));
        ah[1][g] = mf(a1h, bl, mf(a1l, bh, mf(a1h, bh, ah[1][g])));
      }
    }
  }

  const int col = cw + lr;
  const float bx0 = b1[col], bx1 = b1[col + HH], bx2 = b1[col + 2 * HH];
  const float bh0 = b2[col], bh1 = b2[col + HH], bh2 = b2[col + 2 * HH];

#pragma unroll
  for (int f = 0; f < 2; ++f) {
#pragma unroll
    for (int i = 0; i < 4; ++i) {
      const int row = m0 + f * 16 + lq * 4 + i;
      const float rr = sigf(ax[f][0][i] + bx0 + ah[f][0][i] + bh0);
      const float zz = sigf(ax[f][1][i] + bx1 + ah[f][1][i] + bh1);
      const float nn = tanhf(ax[f][2][i] + bx2 + rr * (ah[f][2][i] + bh2));
      const float hp = zero_h ? 0.f : hprev[(size_t)row * HH + col];
      const float hn = (1.f - zz) * nn + zz * hp;
      hout[(size_t)row * HH + col] = hn;
      bf16 sh, sl;
      split2(hn, sh, sl);
      hoh[(size_t)row * HH + col] = sh;
      hol[(size_t)row * HH + col] = sl;
    }
  }
}

// ---------------------------------------------------------------------------
// Output projection, last timestep only (fp32 VALU — tiny, audited):
// o = relu(h1) @ W_out^T + b_out + res; res <- o; d_out[:,d,:] <- o (fp32);
// y-token slot d <- split-bf16(o) for the next windows' L0 ingestion.
// ---------------------------------------------------------------------------
__global__ __launch_bounds__(256) void out_v(
    const float* __restrict__ h1,
    const float* __restrict__ Wo,   // [YY][HH] fp32 (raw W_out)
    const float* __restrict__ bo,
    float* __restrict__ res,
    bf16* __restrict__ yh, bf16* __restrict__ yl,
    float* __restrict__ outp,
    int d)
{
  int idx = blockIdx.x * 256 + threadIdx.x;
  if (idx >= BB * YY) return;
  int col = idx % YY, row = idx / YY;
  const float* hr = h1 + (size_t)row * HH;
  const float* wr = Wo + (size_t)col * HH;
  float acc = 0.f;
#pragma unroll 4
  for (int k = 0; k < HH; k += 4) {
    f4 h = *(const f4*)&hr[k];
    f4 w = *(const f4*)&wr[k];
#pragma unroll
    for (int j = 0; j < 4; ++j) acc = fmaf(fmaxf(h[j], 0.f), w[j], acc);
  }
  float o = acc + bo[col] + res[idx];
  res[idx] = o;
  outp[((size_t)row * DS + d) * YY + col] = o;
  bf16 sh, sl;
  split2(o, sh, sl);
  yh[(size_t)row * YP + col] = sh;
  yl[(size_t)row * YP + col] = sl;
}

extern "C" void kernel_launch(void* const* d_in, const int* in_sizes, int n_in,
                              void* d_out, int out_size, void* d_ws, size_t ws_size,
                              hipStream_t stream)
{
  // role mapping insurance (dict-order signature, greedy fallback)
  static const int sig_dict[11] = {2501632, 288768, 786432, 1536, 1536,
                                   786432, 786432, 1536, 1536, 96256, 188};
  int map[11];
  bool dict_ok = (n_in == 11);
  if (dict_ok)
    for (int r = 0; r < 11; ++r)
      if (in_sizes[r] != sig_dict[r]) { dict_ok = false; break; }
  if (dict_ok) { for (int r = 0; r < 11; ++r) map[r] = r; }
  else {
    bool used[16] = {};
    for (int r = 0; r < 11; ++r) {
      map[r] = r < n_in ? r : 0;
      for (int i = 0; i < n_in && i < 16; ++i)
        if (!used[i] && in_sizes[i] == sig_dict[r]) { map[r] = i; used[i] = true; break; }
    }
  }
  const float* x     = (const float*)d_in[map[0]];
  const float* W_ih0 = (const float*)d_in[map[1]];
  const float* W_hh0 = (const float*)d_in[map[2]];
  const float* b_ih0 = (const float*)d_in[map[3]];
  const float* b_hh0 = (const float*)d_in[map[4]];
  const float* W_ih1 = (const float*)d_in[map[5]];
  const float* W_hh1 = (const float*)d_in[map[6]];
  const float* b_ih1 = (const float*)d_in[map[7]];
  const float* b_hh1 = (const float*)d_in[map[8]];
  const float* W_out = (const float*)d_in[map[9]];
  const float* b_out = (const float*)d_in[map[10]];
  float* outp = (float*)d_out;

  char* p = (char*)d_ws;
  auto alloc = [&](size_t bytes) { char* q = p; p += (bytes + 255) & ~(size_t)255; return q; };
  bf16* xh = (bf16*)alloc((size_t)TT * BB * YP * 2);
  bf16* xl = (bf16*)alloc((size_t)TT * BB * YP * 2);
  bf16* yh = (bf16*)alloc((size_t)DS * BB * YP * 2);
  bf16* yl = (bf16*)alloc((size_t)DS * BB * YP * 2);
  bf16* W0h = (bf16*)alloc((size_t)GG * YP * 2);   // W_ih0 swizzled hi
  bf16* W0l = (bf16*)alloc((size_t)GG * YP * 2);
  bf16* Wh0h = (bf16*)alloc((size_t)GG * HH * 2);  // W_hh0
  bf16* Wh0l = (bf16*)alloc((size_t)GG * HH * 2);
  bf16* Wi1h = (bf16*)alloc((size_t)GG * HH * 2);  // W_ih1
  bf16* Wi1l = (bf16*)alloc((size_t)GG * HH * 2);
  bf16* Wh1h = (bf16*)alloc((size_t)GG * HH * 2);  // W_hh1
  bf16* Wh1l = (bf16*)alloc((size_t)GG * HH * 2);
  float* h0f[2]; float* h1f[2];
  bf16* h0h[2]; bf16* h0l[2]; bf16* h1h[2]; bf16* h1l[2];
  for (int i = 0; i < 2; ++i) {
    h0f[i] = (float*)alloc((size_t)BB * HH * 4);
    h1f[i] = (float*)alloc((size_t)BB * HH * 4);
    h0h[i] = (bf16*)alloc((size_t)BB * HH * 2);
    h0l[i] = (bf16*)alloc((size_t)BB * HH * 2);
    h1h[i] = (bf16*)alloc((size_t)BB * HH * 2);
    h1l[i] = (bf16*)alloc((size_t)BB * HH * 2);
  }
  float* res = (float*)alloc((size_t)BB * YY * 4);

  k_setup_x<<<(TT * BB * YP + 255) / 256, 256, 0, stream>>>(x, xh, xl, yh, yl, res);
  k_swz2<<<(GG / 16) * (YP / 32) * 64 / 256, 256, 0, stream>>>(W_ih0, W0h, W0l, GG, YY, YP);
  k_swz2<<<(GG / 16) * (HH / 32) * 64 / 256, 256, 0, stream>>>(W_hh0, Wh0h, Wh0l, GG, HH, HH);
  k_swz2<<<(GG / 16) * (HH / 32) * 64 / 256, 256, 0, stream>>>(W_ih1, Wi1h, Wi1l, GG, HH, HH);
  k_swz2<<<(GG / 16) * (HH / 32) * 64 / 256, 256, 0, stream>>>(W_hh1, Wh1h, Wh1l, GG, HH, HH);

  const dim3 grid(16, 16);  // 64-row x 32-col tiles over 1024 x 512
  for (int d = 0; d < DS; ++d) {
    for (int t = 0; t < TT; ++t) {
      // window token t of decode step d: originals d+t, else generated t-13+d
      const size_t toff = (t < TT - d) ? (size_t)(d + t) * BB * YP : 0;
      const size_t yoff = (size_t)(t - TT + d) * BB * YP;
      const bf16* t_h = (t < TT - d) ? xh + toff : yh + yoff;
      const bf16* t_l = (t < TT - d) ? xl + toff : yl + yoff;
      const int rd = t & 1, wr = (t + 1) & 1;  // ping-pong h buffers
      gru_m<YP / 32><<<grid, 256, 0, stream>>>(
          t_h, t_l, YP, W0h, W0l, b_ih0,
          h0h[rd], h0l[rd], Wh0h, Wh0l, b_hh0, h0f[rd],
          h0f[wr], h0h[wr], h0l[wr], t == 0);
      gru_m<HH / 32><<<grid, 256, 0, stream>>>(
          h0h[wr], h0l[wr], HH, Wi1h, Wi1l, b_ih1,
          h1h[rd], h1l[rd], Wh1h, Wh1l, b_hh1, h1f[rd],
          h1f[wr], h1h[wr], h1l[wr], t == 0);
    }
    // after t=12 the live h1 buffer is index (12+1)&1 == 1
    out_v<<<(BB * YY + 255) / 256, 256, 0, stream>>>(
        h1f[1], W_out, b_out, res, yh + (size_t)d * BB * YP,
        yl + (size_t)d * BB * YP, outp, d);
  }
}

// Round 8
// 7661.731 us; speedup vs baseline: 3.4369x; 1.5099x over previous
//
#include <hip/hip_runtime.h>
#include <hip/hip_bf16.h>
#include <math.h>

using bf16 = __hip_bfloat16;

#define BB 1024
#define TT 13
#define YY 188
#define HH 512
#define GG 1536
#define YP 192
#define DS 13

typedef __bf16 bf16x8 __attribute__((ext_vector_type(8)));
typedef float f32x4 __attribute__((ext_vector_type(4)));
typedef float f4 __attribute__((ext_vector_type(4)));

__device__ __forceinline__ float sigf(float x) { return 1.f / (1.f + expf(-x)); }
__device__ __forceinline__ bf16x8 ldf(const bf16* p) {
  return *reinterpret_cast<const bf16x8*>(p);
}
__device__ __forceinline__ f32x4 mf(bf16x8 a, bf16x8 b, f32x4 c) {
  return __builtin_amdgcn_mfma_f32_16x16x32_bf16(a, b, c, 0, 0, 0);
}
// load 8 contiguous fp32, split in-register into hi/lo bf16x8 (~16 mantissa bits)
__device__ __forceinline__ void ldsplit(const float* p, bf16x8& hi, bf16x8& lo) {
  f32x4 v0 = *(const f32x4*)p;
  f32x4 v1 = *(const f32x4*)(p + 4);
#pragma unroll
  for (int j = 0; j < 4; ++j) {
    __bf16 h0 = (__bf16)v0[j];
    hi[j] = h0; lo[j] = (__bf16)(v0[j] - (float)h0);
    __bf16 h1 = (__bf16)v1[j];
    hi[j + 4] = h1; lo[j + 4] = (__bf16)(v1[j] - (float)h1);
  }
}
__device__ __forceinline__ void split2(float v, bf16& hi, bf16& lo) {
  hi = __float2bfloat16(v);
  lo = __float2bfloat16(v - __bfloat162float(hi));
}

// Per-phase cell table (<=7 independent (d,t) cells), passed by value.
struct GruPhase {
  int ncells;
  int zmask;            // bit c: t==0 (skip gh GEMM, h_prev = 0)
  unsigned a1off[7];    // element offset into a1base per cell
  unsigned hoff[7];     // h_prev element offset into hbuf per cell
  unsigned ooff[7];     // h_out  element offset into obuf per cell
};

// ---------------------------------------------------------------------------
// Swizzle a row-major (Nsrc x Ksrc) fp32 weight into MFMA B-fragment order,
// split hi/lo, zero-padded to (Npad x Kpad). Frag lane l of tile (nt,kt)
// holds W[nt*16 + (l&15)][kt*32 + (l>>4)*8 + j], j=0..7 contiguous -> each
// kernel-side B-frag load is one coalesced 1 KiB dwordx4 per wave.
// ---------------------------------------------------------------------------
__global__ void k_swz2(const float* __restrict__ src, bf16* __restrict__ dhi,
                       bf16* __restrict__ dlo, int Nsrc, int Ksrc, int Kpad) {
  int idx = blockIdx.x * 256 + threadIdx.x;
  int ks = Kpad >> 5;
  int l = idx & 63;
  int ntkt = idx >> 6;
  int nt = ntkt / ks, kt = ntkt - nt * ks;
  int n = nt * 16 + (l & 15);
  int k0 = kt * 32 + (l >> 4) * 8;
#pragma unroll
  for (int j = 0; j < 8; ++j) {
    int k = k0 + j;
    float v = (n < Nsrc && k < Ksrc) ? src[(size_t)n * Ksrc + k] : 0.f;
    bf16 h, lo;
    split2(v, h, lo);
    dhi[(size_t)idx * 8 + j] = h;
    dlo[(size_t)idx * 8 + j] = lo;
  }
}

// Setup: 26-slot fp32 token buffer (slot s<13: x[:,s,:]; s>=13: y_{s-13}, zeroed
// now, filled by out_v later), plus fp32 residual seeded with x[:,12,:].
__global__ void k_setup(const float* __restrict__ x, float* __restrict__ tok,
                        float* __restrict__ res) {
  int idx = blockIdx.x * 256 + threadIdx.x;
  const int total = 26 * BB * YP;
  if (idx < total) {
    int k = idx % YP;
    int b = (idx / YP) % BB;
    int s = idx / (YP * BB);
    float v = 0.f;
    if (s < TT && k < YY) v = x[((size_t)b * TT + s) * YY + k];
    tok[idx] = v;
  }
  if (idx < BB * YY) {
    int yy = idx % YY;
    int b = idx / YY;
    res[idx] = x[((size_t)b * TT + 12) * YY + yy];
  }
}

// ---------------------------------------------------------------------------
// Phase-batched GRU step, split-bf16 MFMA (3-term AhiWhi+AloWhi+AhiWlo):
//   xg = A1 @ W1^T (K = K1S*32);  gh = h_prev @ W2^T (K = 512, skip if zmask)
//   r = sig(xgr+ghr+b); z = sig(...); n = tanh(xgn+bxn + r*(ghn+bhn))
//   h = (1-z)*n + z*h_prev
// Grid: x = ncells*16 row-tiles (64 rows), y = 16 col-groups (32 h-cols).
// Block: 4 waves (2 row x 2 col); wave = 32 rows x 16 cols x 3 gates.
// A operands fp32 in memory, hi/lo split in-register; B pre-swizzled hi/lo.
// ---------------------------------------------------------------------------
template <int K1S>
__global__ __launch_bounds__(256) void gru_p(
    const float* __restrict__ a1base, int lda1,
    const bf16* __restrict__ W1h, const bf16* __restrict__ W1l,
    const float* __restrict__ b1,
    const float* __restrict__ hbuf,
    const bf16* __restrict__ W2h, const bf16* __restrict__ W2l,
    const float* __restrict__ b2,
    float* __restrict__ obuf,
    GruPhase ph)
{
  const int cell = blockIdx.x >> 4;
  const int rt   = blockIdx.x & 15;
  const int w  = threadIdx.x >> 6;
  const int l  = threadIdx.x & 63;
  const int lr = l & 15;
  const int lq = l >> 4;
  const int kq = lq * 8;
  const int m0 = rt * 64 + (w >> 1) * 32;
  const int cw = blockIdx.y * 32 + (w & 1) * 16;
  const int nt0 = cw >> 4;
  const float* A1 = a1base + ph.a1off[cell];
  const float* HP = hbuf + ph.hoff[cell];
  float* HO = obuf + ph.ooff[cell];
  const int zero_h = (ph.zmask >> cell) & 1;

  const f32x4 vzero = {0.f, 0.f, 0.f, 0.f};
  f32x4 ax[2][3], ah[2][3];
#pragma unroll
  for (int f = 0; f < 2; ++f)
#pragma unroll
    for (int g = 0; g < 3; ++g) { ax[f][g] = vzero; ah[f][g] = vzero; }

#pragma unroll 2
  for (int kt = 0; kt < K1S; ++kt) {
    bf16x8 a0h, a0l, a1h, a1l;
    ldsplit(A1 + (size_t)(m0 + lr) * lda1 + kt * 32 + kq, a0h, a0l);
    ldsplit(A1 + (size_t)(m0 + 16 + lr) * lda1 + kt * 32 + kq, a1h, a1l);
#pragma unroll
    for (int g = 0; g < 3; ++g) {
      size_t off = ((size_t)((nt0 + g * 32) * K1S + kt) * 64 + l) * 8;
      bf16x8 bh = ldf(W1h + off);
      bf16x8 bl = ldf(W1l + off);
      ax[0][g] = mf(a0h, bl, mf(a0l, bh, mf(a0h, bh, ax[0][g])));
      ax[1][g] = mf(a1h, bl, mf(a1l, bh, mf(a1h, bh, ax[1][g])));
    }
  }
  if (!zero_h) {
#pragma unroll 2
    for (int kt = 0; kt < HH / 32; ++kt) {
      bf16x8 a0h, a0l, a1h, a1l;
      ldsplit(HP + (size_t)(m0 + lr) * HH + kt * 32 + kq, a0h, a0l);
      ldsplit(HP + (size_t)(m0 + 16 + lr) * HH + kt * 32 + kq, a1h, a1l);
#pragma unroll
      for (int g = 0; g < 3; ++g) {
        size_t off = ((size_t)((nt0 + g * 32) * (HH / 32) + kt) * 64 + l) * 8;
        bf16x8 bh = ldf(W2h + off);
        bf16x8 bl = ldf(W2l + off);
        ah[0][g] = mf(a0h, bl, mf(a0l, bh, mf(a0h, bh, ah[0][g])));
        ah[1][g] = mf(a1h, bl, mf(a1l, bh, mf(a1h, bh, ah[1][g])));
      }
    }
  }

  const int col = cw + lr;
  const float bx0 = b1[col], bx1 = b1[col + HH], bx2 = b1[col + 2 * HH];
  const float bh0 = b2[col], bh1 = b2[col + HH], bh2 = b2[col + 2 * HH];

#pragma unroll
  for (int f = 0; f < 2; ++f) {
#pragma unroll
    for (int i = 0; i < 4; ++i) {
      const int row = m0 + f * 16 + lq * 4 + i;
      const float rr = sigf(ax[f][0][i] + bx0 + ah[f][0][i] + bh0);
      const float zz = sigf(ax[f][1][i] + bx1 + ah[f][1][i] + bh1);
      const float nn = tanhf(ax[f][2][i] + bx2 + rr * (ah[f][2][i] + bh2));
      const float hp = zero_h ? 0.f : HP[(size_t)row * HH + col];
      HO[(size_t)row * HH + col] = (1.f - zz) * nn + zz * hp;
    }
  }
}

// ---------------------------------------------------------------------------
// Output projection, last timestep only (fp32 VALU):
// o = relu(h1) @ W_out^T + b_out + res; res <- o; d_out[:,d,:] <- o (fp32);
// token slot 13+d <- o (fp32 feedback, pad cols stay 0 from setup).
// ---------------------------------------------------------------------------
__global__ __launch_bounds__(256) void out_v(
    const float* __restrict__ h1,
    const float* __restrict__ Wo,
    const float* __restrict__ bo,
    float* __restrict__ res,
    float* __restrict__ ytok,
    float* __restrict__ outp,
    int d)
{
  int idx = blockIdx.x * 256 + threadIdx.x;
  if (idx >= BB * YY) return;
  int col = idx % YY, row = idx / YY;
  const float* hr = h1 + (size_t)row * HH;
  const float* wr = Wo + (size_t)col * HH;
  float acc = 0.f;
#pragma unroll 4
  for (int k = 0; k < HH; k += 4) {
    f4 h = *(const f4*)&hr[k];
    f4 w = *(const f4*)&wr[k];
#pragma unroll
    for (int j = 0; j < 4; ++j) acc = fmaf(fmaxf(h[j], 0.f), w[j], acc);
  }
  float o = acc + bo[col] + res[idx];
  res[idx] = o;
  outp[((size_t)row * DS + d) * YY + col] = o;
  ytok[(size_t)row * YP + col] = o;
}

extern "C" void kernel_launch(void* const* d_in, const int* in_sizes, int n_in,
                              void* d_out, int out_size, void* d_ws, size_t ws_size,
                              hipStream_t stream)
{
  // role mapping insurance (dict-order signature, greedy fallback)
  static const int sig_dict[11] = {2501632, 288768, 786432, 1536, 1536,
                                   786432, 786432, 1536, 1536, 96256, 188};
  int map[11];
  bool dict_ok = (n_in == 11);
  if (dict_ok)
    for (int r = 0; r < 11; ++r)
      if (in_sizes[r] != sig_dict[r]) { dict_ok = false; break; }
  if (dict_ok) { for (int r = 0; r < 11; ++r) map[r] = r; }
  else {
    bool used[16] = {};
    for (int r = 0; r < 11; ++r) {
      map[r] = r < n_in ? r : 0;
      for (int i = 0; i < n_in && i < 16; ++i)
        if (!used[i] && in_sizes[i] == sig_dict[r]) { map[r] = i; used[i] = true; break; }
    }
  }
  const float* x     = (const float*)d_in[map[0]];
  const float* W_ih0 = (const float*)d_in[map[1]];
  const float* W_hh0 = (const float*)d_in[map[2]];
  const float* b_ih0 = (const float*)d_in[map[3]];
  const float* b_hh0 = (const float*)d_in[map[4]];
  const float* W_ih1 = (const float*)d_in[map[5]];
  const float* W_hh1 = (const float*)d_in[map[6]];
  const float* b_ih1 = (const float*)d_in[map[7]];
  const float* b_hh1 = (const float*)d_in[map[8]];
  const float* W_out = (const float*)d_in[map[9]];
  const float* b_out = (const float*)d_in[map[10]];
  float* outp = (float*)d_out;

  char* p = (char*)d_ws;
  auto alloc = [&](size_t bytes) { char* q = p; p += (bytes + 255) & ~(size_t)255; return q; };
  float* tokens = (float*)alloc((size_t)26 * BB * YP * 4);   // 20.4 MB
  bf16* W0h  = (bf16*)alloc((size_t)GG * YP * 2);            // W_ih0 swz hi
  bf16* W0l  = (bf16*)alloc((size_t)GG * YP * 2);
  bf16* Wh0h = (bf16*)alloc((size_t)GG * HH * 2);            // W_hh0
  bf16* Wh0l = (bf16*)alloc((size_t)GG * HH * 2);
  bf16* Wi1h = (bf16*)alloc((size_t)GG * HH * 2);            // W_ih1
  bf16* Wi1l = (bf16*)alloc((size_t)GG * HH * 2);
  bf16* Wh1h = (bf16*)alloc((size_t)GG * HH * 2);            // W_hh1
  bf16* Wh1l = (bf16*)alloc((size_t)GG * HH * 2);
  float* h0buf = (float*)alloc((size_t)2 * 7 * BB * HH * 4); // 29.4 MB (parity x d%7)
  float* h1buf = (float*)alloc((size_t)2 * 7 * BB * HH * 4); // 29.4 MB
  float* res   = (float*)alloc((size_t)BB * YY * 4);

  k_setup<<<(26 * BB * YP + 255) / 256, 256, 0, stream>>>(x, tokens, res);
  k_swz2<<<(GG / 16) * (YP / 32) * 64 / 256, 256, 0, stream>>>(W_ih0, W0h, W0l, GG, YY, YP);
  k_swz2<<<(GG / 16) * (HH / 32) * 64 / 256, 256, 0, stream>>>(W_hh0, Wh0h, Wh0l, GG, HH, HH);
  k_swz2<<<(GG / 16) * (HH / 32) * 64 / 256, 256, 0, stream>>>(W_ih1, Wi1h, Wi1l, GG, HH, HH);
  k_swz2<<<(GG / 16) * (HH / 32) * 64 / 256, 256, 0, stream>>>(W_hh1, Wh1h, Wh1l, GG, HH, HH);

  // Diagonal wavefront: phase(d,t) = t + 2d, 37 phases of up to 7 cells.
  // All cells in phase p read h-parity (p-1)&1, write p&1; d-slots mod 7.
  for (int phs = 0; phs < 37; ++phs) {
    GruPhase P0{}, P1{};
    const int pprev = (phs + 1) & 1, pcur = phs & 1;
    int C = 0;
    for (int d = 0; d < DS; ++d) {
      int t = phs - 2 * d;
      if (t < 0 || t > 12) continue;
      int c = C++;
      P0.a1off[c] = (unsigned)((d + t) * BB * YP);             // token slot d+t
      P0.hoff[c]  = (unsigned)((pprev * 7 + d % 7) * BB * HH);
      P0.ooff[c]  = (unsigned)((pcur * 7 + d % 7) * BB * HH);
      if (t == 0) P0.zmask |= 1 << c;
      P1.a1off[c] = P0.ooff[c];   // L1 input = L0 output of this phase
      P1.hoff[c]  = P0.hoff[c];
      P1.ooff[c]  = P0.ooff[c];
    }
    P0.ncells = P1.ncells = C;
    P1.zmask = P0.zmask;
    const dim3 grid(C * 16, 16);
    gru_p<YP / 32><<<grid, 256, 0, stream>>>(tokens, YP, W0h, W0l, b_ih0,
                                             h0buf, Wh0h, Wh0l, b_hh0, h0buf, P0);
    gru_p<HH / 32><<<grid, 256, 0, stream>>>(h0buf, HH, Wi1h, Wi1l, b_ih1,
                                             h1buf, Wh1h, Wh1l, b_hh1, h1buf, P1);
    // decode step d finishes at phase 12+2d: project + feed back token 13+d
    if (phs >= 12 && ((phs - 12) & 1) == 0) {
      const int d = (phs - 12) / 2;
      out_v<<<(BB * YY + 255) / 256, 256, 0, stream>>>(
          h1buf + (size_t)(pcur * 7 + d % 7) * BB * HH, W_out, b_out, res,
          tokens + (size_t)(13 + d) * BB * YP, outp, d);
    }
  }
}

// Round 9
// 7157.627 us; speedup vs baseline: 3.6790x; 1.0704x over previous
//
#include <hip/hip_runtime.h>
#include <hip/hip_bf16.h>
#include <math.h>

using bf16 = __hip_bfloat16;

#define BB 1024
#define TT 13
#define YY 188
#define HH 512
#define GG 1536
#define YP 192
#define DS 13

typedef __bf16 bf16x8 __attribute__((ext_vector_type(8)));
typedef float f32x4 __attribute__((ext_vector_type(4)));
typedef float f4 __attribute__((ext_vector_type(4)));

__device__ __forceinline__ float sigf(float x) { return 1.f / (1.f + expf(-x)); }
__device__ __forceinline__ bf16x8 ldf(const bf16* p) {
  return *reinterpret_cast<const bf16x8*>(p);
}
__device__ __forceinline__ f32x4 mf(bf16x8 a, bf16x8 b, f32x4 c) {
  return __builtin_amdgcn_mfma_f32_16x16x32_bf16(a, b, c, 0, 0, 0);
}
__device__ __forceinline__ void split2(float v, bf16& hi, bf16& lo) {
  hi = __float2bfloat16(v);
  lo = __float2bfloat16(v - __bfloat162float(hi));
}

// Per-phase cell table (<=7 independent (d,t) cells), passed by value.
struct GruPhase {
  int ncells;
  int zmask;            // bit c: t==0 (skip gh GEMM, h_prev = 0)
  unsigned a1off[7];    // element offset into the A1 hi/lo arrays per cell
  unsigned hoff[7];     // h_prev element offset into h hi/lo arrays per cell
  unsigned ooff[7];     // h_out  element offset per cell
};

// ---------------------------------------------------------------------------
// Swizzle a row-major (Nsrc x Ksrc) fp32 weight into MFMA B-fragment order,
// split hi/lo, zero-padded to (Npad x Kpad). Frag lane l of tile (nt,kt)
// holds W[nt*16 + (l&15)][kt*32 + (l>>4)*8 + j], j=0..7 contiguous -> each
// kernel-side B-frag load is one coalesced 1 KiB dwordx4 per wave.
// ---------------------------------------------------------------------------
__global__ void k_swz2(const float* __restrict__ src, bf16* __restrict__ dhi,
                       bf16* __restrict__ dlo, int Nsrc, int Ksrc, int Kpad) {
  int idx = blockIdx.x * 256 + threadIdx.x;
  int ks = Kpad >> 5;
  int l = idx & 63;
  int ntkt = idx >> 6;
  int nt = ntkt / ks, kt = ntkt - nt * ks;
  int n = nt * 16 + (l & 15);
  int k0 = kt * 32 + (l >> 4) * 8;
#pragma unroll
  for (int j = 0; j < 8; ++j) {
    int k = k0 + j;
    float v = (n < Nsrc && k < Ksrc) ? src[(size_t)n * Ksrc + k] : 0.f;
    bf16 h, lo;
    split2(v, h, lo);
    dhi[(size_t)idx * 8 + j] = h;
    dlo[(size_t)idx * 8 + j] = lo;
  }
}

// Setup: 26-slot hi/lo token buffers (slot s<13: x[:,s,:]; s>=13: y_{s-13},
// zeroed, filled by out_v), plus fp32 residual seeded with x[:,12,:].
__global__ void k_setup(const float* __restrict__ x, bf16* __restrict__ th,
                        bf16* __restrict__ tl, float* __restrict__ res) {
  int idx = blockIdx.x * 256 + threadIdx.x;
  const int total = 26 * BB * YP;
  if (idx < total) {
    int k = idx % YP;
    int b = (idx / YP) % BB;
    int s = idx / (YP * BB);
    float v = 0.f;
    if (s < TT && k < YY) v = x[((size_t)b * TT + s) * YY + k];
    bf16 h, lo;
    split2(v, h, lo);
    th[idx] = h; tl[idx] = lo;
  }
  if (idx < BB * YY) {
    int yy = idx % YY;
    int b = idx / YY;
    res[idx] = x[((size_t)b * TT + 12) * YY + yy];
  }
}

// ---------------------------------------------------------------------------
// Phase-batched GRU step, split-bf16 MFMA (3-term AhiWhi+AloWhi+AhiWlo).
// A operands are PRE-SPLIT hi/lo bf16 in memory (split once at production —
// round-8's in-loop split was replicated x16 across col-group blocks and
// made VALU ~= MFMA; this removes it).
//   xg = A1 @ W1^T (K = K1S*32);  gh = h_prev @ W2^T (K = 512, skip if zmask)
//   r = sig(xgr+ghr+b); z = sig(...); n = tanh(xgn+bxn + r*(ghn+bhn))
//   h = (1-z)*n + z*h_prev,  h_prev = hi+lo reconstruction (2^-17 rel)
// Grid: x = ncells*16 row-tiles (64 rows), y = 16 col-groups (32 h-cols).
// Block: 4 waves (2 row x 2 col); wave = 32 rows x 16 cols x 3 gates.
// ---------------------------------------------------------------------------
template <int K1S>
__global__ __launch_bounds__(256) void gru_p(
    const bf16* __restrict__ a1h, const bf16* __restrict__ a1l, int lda1,
    const bf16* __restrict__ W1h, const bf16* __restrict__ W1l,
    const float* __restrict__ b1,
    const bf16* __restrict__ hbh, const bf16* __restrict__ hbl,
    const bf16* __restrict__ W2h, const bf16* __restrict__ W2l,
    const float* __restrict__ b2,
    bf16* __restrict__ obh, bf16* __restrict__ obl,
    GruPhase ph)
{
  const int cell = blockIdx.x >> 4;
  const int rt   = blockIdx.x & 15;
  const int w  = threadIdx.x >> 6;
  const int l  = threadIdx.x & 63;
  const int lr = l & 15;
  const int lq = l >> 4;
  const int kq = lq * 8;
  const int m0 = rt * 64 + (w >> 1) * 32;
  const int cw = blockIdx.y * 32 + (w & 1) * 16;
  const int nt0 = cw >> 4;
  const bf16* A1h = a1h + ph.a1off[cell];
  const bf16* A1l = a1l + ph.a1off[cell];
  const bf16* HPh = hbh + ph.hoff[cell];
  const bf16* HPl = hbl + ph.hoff[cell];
  bf16* HOh = obh + ph.ooff[cell];
  bf16* HOl = obl + ph.ooff[cell];
  const int zero_h = (ph.zmask >> cell) & 1;

  const f32x4 vzero = {0.f, 0.f, 0.f, 0.f};
  f32x4 ax[2][3], ah[2][3];
#pragma unroll
  for (int f = 0; f < 2; ++f)
#pragma unroll
    for (int g = 0; g < 3; ++g) { ax[f][g] = vzero; ah[f][g] = vzero; }

#pragma unroll 2
  for (int kt = 0; kt < K1S; ++kt) {
    bf16x8 a0h = ldf(A1h + (size_t)(m0 + lr) * lda1 + kt * 32 + kq);
    bf16x8 a0l = ldf(A1l + (size_t)(m0 + lr) * lda1 + kt * 32 + kq);
    bf16x8 a1hv = ldf(A1h + (size_t)(m0 + 16 + lr) * lda1 + kt * 32 + kq);
    bf16x8 a1lv = ldf(A1l + (size_t)(m0 + 16 + lr) * lda1 + kt * 32 + kq);
#pragma unroll
    for (int g = 0; g < 3; ++g) {
      size_t off = ((size_t)((nt0 + g * 32) * K1S + kt) * 64 + l) * 8;
      bf16x8 bh = ldf(W1h + off);
      bf16x8 bl = ldf(W1l + off);
      ax[0][g] = mf(a0h, bl, mf(a0l, bh, mf(a0h, bh, ax[0][g])));
      ax[1][g] = mf(a1hv, bl, mf(a1lv, bh, mf(a1hv, bh, ax[1][g])));
    }
  }
  if (!zero_h) {
#pragma unroll 2
    for (int kt = 0; kt < HH / 32; ++kt) {
      bf16x8 a0h = ldf(HPh + (size_t)(m0 + lr) * HH + kt * 32 + kq);
      bf16x8 a0l = ldf(HPl + (size_t)(m0 + lr) * HH + kt * 32 + kq);
      bf16x8 a1hv = ldf(HPh + (size_t)(m0 + 16 + lr) * HH + kt * 32 + kq);
      bf16x8 a1lv = ldf(HPl + (size_t)(m0 + 16 + lr) * HH + kt * 32 + kq);
#pragma unroll
      for (int g = 0; g < 3; ++g) {
        size_t off = ((size_t)((nt0 + g * 32) * (HH / 32) + kt) * 64 + l) * 8;
        bf16x8 bh = ldf(W2h + off);
        bf16x8 bl = ldf(W2l + off);
        ah[0][g] = mf(a0h, bl, mf(a0l, bh, mf(a0h, bh, ah[0][g])));
        ah[1][g] = mf(a1hv, bl, mf(a1lv, bh, mf(a1hv, bh, ah[1][g])));
      }
    }
  }

  const int col = cw + lr;
  const float bx0 = b1[col], bx1 = b1[col + HH], bx2 = b1[col + 2 * HH];
  const float bh0 = b2[col], bh1 = b2[col + HH], bh2 = b2[col + 2 * HH];

#pragma unroll
  for (int f = 0; f < 2; ++f) {
#pragma unroll
    for (int i = 0; i < 4; ++i) {
      const int row = m0 + f * 16 + lq * 4 + i;
      const float rr = sigf(ax[f][0][i] + bx0 + ah[f][0][i] + bh0);
      const float zz = sigf(ax[f][1][i] + bx1 + ah[f][1][i] + bh1);
      const float nn = tanhf(ax[f][2][i] + bx2 + rr * (ah[f][2][i] + bh2));
      float hp = 0.f;
      if (!zero_h) {
        size_t hidx = (size_t)row * HH + col;
        hp = __bfloat162float(HPh[hidx]) + __bfloat162float(HPl[hidx]);
      }
      const float hn = (1.f - zz) * nn + zz * hp;
      bf16 sh, sl;
      split2(hn, sh, sl);
      size_t oidx = (size_t)row * HH + col;
      HOh[oidx] = sh;
      HOl[oidx] = sl;
    }
  }
}

// ---------------------------------------------------------------------------
// Output projection, last timestep only (fp32 VALU):
// o = relu(h1) @ W_out^T + b_out + res; res <- o; d_out[:,d,:] <- o (fp32);
// token slot 13+d <- split-bf16(o).  h1 comes in as hi/lo bf16.
// ---------------------------------------------------------------------------
__global__ __launch_bounds__(256) void out_v(
    const bf16* __restrict__ h1h, const bf16* __restrict__ h1l,
    const float* __restrict__ Wo,
    const float* __restrict__ bo,
    float* __restrict__ res,
    bf16* __restrict__ yh, bf16* __restrict__ yl,
    float* __restrict__ outp,
    int d)
{
  int idx = blockIdx.x * 256 + threadIdx.x;
  if (idx >= BB * YY) return;
  int col = idx % YY, row = idx / YY;
  const bf16* hrh = h1h + (size_t)row * HH;
  const bf16* hrl = h1l + (size_t)row * HH;
  const float* wr = Wo + (size_t)col * HH;
  float acc = 0.f;
#pragma unroll 2
  for (int k = 0; k < HH; k += 8) {
    bf16x8 hh = ldf(hrh + k);
    bf16x8 hl = ldf(hrl + k);
    f4 w0 = *(const f4*)&wr[k];
    f4 w1 = *(const f4*)&wr[k + 4];
#pragma unroll
    for (int j = 0; j < 4; ++j) {
      float hv0 = (float)hh[j] + (float)hl[j];
      float hv1 = (float)hh[j + 4] + (float)hl[j + 4];
      acc = fmaf(fmaxf(hv0, 0.f), w0[j], acc);
      acc = fmaf(fmaxf(hv1, 0.f), w1[j], acc);
    }
  }
  float o = acc + bo[col] + res[idx];
  res[idx] = o;
  outp[((size_t)row * DS + d) * YY + col] = o;
  bf16 sh, sl;
  split2(o, sh, sl);
  yh[(size_t)row * YP + col] = sh;
  yl[(size_t)row * YP + col] = sl;
}

extern "C" void kernel_launch(void* const* d_in, const int* in_sizes, int n_in,
                              void* d_out, int out_size, void* d_ws, size_t ws_size,
                              hipStream_t stream)
{
  // role mapping insurance (dict-order signature, greedy fallback)
  static const int sig_dict[11] = {2501632, 288768, 786432, 1536, 1536,
                                   786432, 786432, 1536, 1536, 96256, 188};
  int map[11];
  bool dict_ok = (n_in == 11);
  if (dict_ok)
    for (int r = 0; r < 11; ++r)
      if (in_sizes[r] != sig_dict[r]) { dict_ok = false; break; }
  if (dict_ok) { for (int r = 0; r < 11; ++r) map[r] = r; }
  else {
    bool used[16] = {};
    for (int r = 0; r < 11; ++r) {
      map[r] = r < n_in ? r : 0;
      for (int i = 0; i < n_in && i < 16; ++i)
        if (!used[i] && in_sizes[i] == sig_dict[r]) { map[r] = i; used[i] = true; break; }
    }
  }
  const float* x     = (const float*)d_in[map[0]];
  const float* W_ih0 = (const float*)d_in[map[1]];
  const float* W_hh0 = (const float*)d_in[map[2]];
  const float* b_ih0 = (const float*)d_in[map[3]];
  const float* b_hh0 = (const float*)d_in[map[4]];
  const float* W_ih1 = (const float*)d_in[map[5]];
  const float* W_hh1 = (const float*)d_in[map[6]];
  const float* b_ih1 = (const float*)d_in[map[7]];
  const float* b_hh1 = (const float*)d_in[map[8]];
  const float* W_out = (const float*)d_in[map[9]];
  const float* b_out = (const float*)d_in[map[10]];
  float* outp = (float*)d_out;

  char* p = (char*)d_ws;
  auto alloc = [&](size_t bytes) { char* q = p; p += (bytes + 255) & ~(size_t)255; return q; };
  bf16* tokh = (bf16*)alloc((size_t)26 * BB * YP * 2);       // 9.8 MB
  bf16* tokl = (bf16*)alloc((size_t)26 * BB * YP * 2);
  bf16* W0h  = (bf16*)alloc((size_t)GG * YP * 2);            // W_ih0 swz hi
  bf16* W0l  = (bf16*)alloc((size_t)GG * YP * 2);
  bf16* Wh0h = (bf16*)alloc((size_t)GG * HH * 2);            // W_hh0
  bf16* Wh0l = (bf16*)alloc((size_t)GG * HH * 2);
  bf16* Wi1h = (bf16*)alloc((size_t)GG * HH * 2);            // W_ih1
  bf16* Wi1l = (bf16*)alloc((size_t)GG * HH * 2);
  bf16* Wh1h = (bf16*)alloc((size_t)GG * HH * 2);            // W_hh1
  bf16* Wh1l = (bf16*)alloc((size_t)GG * HH * 2);
  // h state: parity(2) x d%7 slots, hi/lo bf16
  bf16* h0h = (bf16*)alloc((size_t)2 * 7 * BB * HH * 2);     // 14.7 MB
  bf16* h0l = (bf16*)alloc((size_t)2 * 7 * BB * HH * 2);
  bf16* h1h = (bf16*)alloc((size_t)2 * 7 * BB * HH * 2);
  bf16* h1l = (bf16*)alloc((size_t)2 * 7 * BB * HH * 2);
  float* res = (float*)alloc((size_t)BB * YY * 4);

  k_setup<<<(26 * BB * YP + 255) / 256, 256, 0, stream>>>(x, tokh, tokl, res);
  k_swz2<<<(GG / 16) * (YP / 32) * 64 / 256, 256, 0, stream>>>(W_ih0, W0h, W0l, GG, YY, YP);
  k_swz2<<<(GG / 16) * (HH / 32) * 64 / 256, 256, 0, stream>>>(W_hh0, Wh0h, Wh0l, GG, HH, HH);
  k_swz2<<<(GG / 16) * (HH / 32) * 64 / 256, 256, 0, stream>>>(W_ih1, Wi1h, Wi1l, GG, HH, HH);
  k_swz2<<<(GG / 16) * (HH / 32) * 64 / 256, 256, 0, stream>>>(W_hh1, Wh1h, Wh1l, GG, HH, HH);

  // Diagonal wavefront: phase(d,t) = t + 2d, 37 phases of up to 7 cells.
  // All cells in phase p read h-parity (p-1)&1, write p&1; d-slots mod 7.
  for (int phs = 0; phs < 37; ++phs) {
    GruPhase P0{}, P1{};
    const int pprev = (phs + 1) & 1, pcur = phs & 1;
    int C = 0;
    for (int d = 0; d < DS; ++d) {
      int t = phs - 2 * d;
      if (t < 0 || t > 12) continue;
      int c = C++;
      P0.a1off[c] = (unsigned)((d + t) * BB * YP);             // token slot d+t
      P0.hoff[c]  = (unsigned)((pprev * 7 + d % 7) * BB * HH);
      P0.ooff[c]  = (unsigned)((pcur * 7 + d % 7) * BB * HH);
      if (t == 0) P0.zmask |= 1 << c;
      P1.a1off[c] = P0.ooff[c];   // L1 input = L0 output of this phase
      P1.hoff[c]  = P0.hoff[c];
      P1.ooff[c]  = P0.ooff[c];
    }
    P0.ncells = P1.ncells = C;
    P1.zmask = P0.zmask;
    const dim3 grid(C * 16, 16);
    gru_p<YP / 32><<<grid, 256, 0, stream>>>(tokh, tokl, YP, W0h, W0l, b_ih0,
                                             h0h, h0l, Wh0h, Wh0l, b_hh0,
                                             h0h, h0l, P0);
    gru_p<HH / 32><<<grid, 256, 0, stream>>>(h0h, h0l, HH, Wi1h, Wi1l, b_ih1,
                                             h1h, h1l, Wh1h, Wh1l, b_hh1,
                                             h1h, h1l, P1);
    // decode step d finishes at phase 12+2d: project + feed back token 13+d
    if (phs >= 12 && ((phs - 12) & 1) == 0) {
      const int d = (phs - 12) / 2;
      const size_t hoff = (size_t)(pcur * 7 + d % 7) * BB * HH;
      out_v<<<(BB * YY + 255) / 256, 256, 0, stream>>>(
          h1h + hoff, h1l + hoff, W_out, b_out, res,
          tokh + (size_t)(13 + d) * BB * YP, tokl + (size_t)(13 + d) * BB * YP,
          outp, d);
    }
  }
}

// Round 10
// 5446.646 us; speedup vs baseline: 4.8347x; 1.3141x over previous
//
#include <hip/hip_runtime.h>
#include <hip/hip_bf16.h>
#include <math.h>

using bf16 = __hip_bfloat16;

#define BB 1024
#define TT 13
#define YY 188
#define HH 512
#define GG 1536
#define YP 192
#define DS 13
#define NT 96   // GG/16 B-tiles along the gate dimension

typedef __bf16 bf16x8 __attribute__((ext_vector_type(8)));
typedef float f32x4 __attribute__((ext_vector_type(4)));
typedef float f4 __attribute__((ext_vector_type(4)));

__device__ __forceinline__ float sigf(float x) { return 1.f / (1.f + expf(-x)); }
__device__ __forceinline__ bf16x8 ldf(const bf16* p) {
  return *reinterpret_cast<const bf16x8*>(p);
}
__device__ __forceinline__ f32x4 mf(bf16x8 a, bf16x8 b, f32x4 c) {
  return __builtin_amdgcn_mfma_f32_16x16x32_bf16(a, b, c, 0, 0, 0);
}
__device__ __forceinline__ void split2(float v, bf16& hi, bf16& lo) {
  hi = __float2bfloat16(v);
  lo = __float2bfloat16(v - __bfloat162float(hi));
}

// Per-phase cell table (<=13 independent (d,t) cells), passed by value.
struct GruPhase {
  int ncells;
  int zmask;             // bit c: t==0 (skip gh GEMM, h_prev = 0)
  unsigned a1off[13];    // A1 element offset per cell
  unsigned hoff[13];     // h_prev element offset per cell
  unsigned ooff[13];     // h_out  element offset per cell
};

// ---------------------------------------------------------------------------
// Swizzle a row-major (Nsrc x Ksrc) fp32 weight into KT-MAJOR MFMA B-frag
// order, split hi/lo, zero-padded. Tile (kt,nt) at elem (kt*NT + nt)*512;
// lane l holds W[nt*16+(l&15)][kt*32+(l>>4)*8+j], j=0..7 contiguous.
// kt-major => a block's per-kt B slice is contiguous per gate (LDS staging).
// ---------------------------------------------------------------------------
__global__ void k_swz2(const float* __restrict__ src, bf16* __restrict__ dhi,
                       bf16* __restrict__ dlo, int Nsrc, int Ksrc) {
  int idx = blockIdx.x * 256 + threadIdx.x;   // ((kt*NT+nt), lane)
  int l = idx & 63;
  int ktnt = idx >> 6;
  int nt = ktnt % NT, kt = ktnt / NT;
  int n = nt * 16 + (l & 15);
  int k0 = kt * 32 + (l >> 4) * 8;
#pragma unroll
  for (int j = 0; j < 8; ++j) {
    int k = k0 + j;
    float v = (n < Nsrc && k < Ksrc) ? src[(size_t)n * Ksrc + k] : 0.f;
    bf16 h, lo;
    split2(v, h, lo);
    dhi[(size_t)idx * 8 + j] = h;
    dlo[(size_t)idx * 8 + j] = lo;
  }
}

// Setup: 26-slot hi/lo token buffers (s<13: x[:,s,:]; s>=13: y_{s-13}), plus
// fp32 residual seeded with x[:,12,:].
__global__ void k_setup(const float* __restrict__ x, bf16* __restrict__ th,
                        bf16* __restrict__ tl, float* __restrict__ res) {
  int idx = blockIdx.x * 256 + threadIdx.x;
  const int total = 26 * BB * YP;
  if (idx < total) {
    int k = idx % YP;
    int b = (idx / YP) % BB;
    int s = idx / (YP * BB);
    float v = 0.f;
    if (s < TT && k < YY) v = x[((size_t)b * TT + s) * YY + k];
    bf16 h, lo;
    split2(v, h, lo);
    th[idx] = h; tl[idx] = lo;
  }
  if (idx < BB * YY) {
    int yy = idx % YY;
    int b = idx / YY;
    res[idx] = x[((size_t)b * TT + 12) * YY + yy];
  }
}

// ---------------------------------------------------------------------------
// Phase-batched GRU step v2: LDS-staged B, 128x32 block tile.
// 3-term split-bf16 MFMA; r/z accumulate xg+gh jointly, n kept separate.
// Block: 256 thr = 4 waves, each 32 rows x 32 cols x 3 gates.
// Grid: x = 16 col-groups (32 cols) -> XCD = colgroup%8 (weight L2 locality),
//       y = ncells*8 row-tiles (128 rows).
// Per kt: stage 12 KiB B-slice (3g x 2nt x hi/lo) into LDS dbuf (1 barrier),
// 4 A-frag global loads + 12 ds_read_b128 + 36 MFMA per wave.
// ---------------------------------------------------------------------------
template <int KT1>
__global__ __launch_bounds__(256) void gru2(
    const bf16* __restrict__ a1h, const bf16* __restrict__ a1l, int lda1,
    const bf16* __restrict__ W1h, const bf16* __restrict__ W1l,
    const float* __restrict__ b1,
    const bf16* __restrict__ hbh, const bf16* __restrict__ hbl,
    const bf16* __restrict__ W2h, const bf16* __restrict__ W2l,
    const float* __restrict__ b2,
    bf16* __restrict__ obh, bf16* __restrict__ obl,
    GruPhase ph)
{
  __shared__ __align__(16) __bf16 Bl[2][12][512];
  const int tid = threadIdx.x;
  const int w = tid >> 6, l = tid & 63;
  const int lr = l & 15, lq = l >> 4, kq = lq * 8;
  const int cell = blockIdx.y >> 3, rt = blockIdx.y & 7;
  const int cw = blockIdx.x * 32;
  const int m0 = rt * 128 + w * 32;
  const bf16* A1h = a1h + ph.a1off[cell];
  const bf16* A1l = a1l + ph.a1off[cell];
  const bf16* HPh = hbh + ph.hoff[cell];
  const bf16* HPl = hbl + ph.hoff[cell];
  bf16* HOh = obh + ph.ooff[cell];
  bf16* HOl = obl + ph.ooff[cell];
  const int zero_h = (ph.zmask >> cell) & 1;

  const f32x4 vzero = {0.f, 0.f, 0.f, 0.f};
  f32x4 arz[2][2][2];           // [rf][r/z][ntl] : xg+gh joint accumulation
  f32x4 axn[2][2], ahn[2][2];   // n-gate parts kept separate
#pragma unroll
  for (int rf = 0; rf < 2; ++rf)
#pragma unroll
    for (int ntl = 0; ntl < 2; ++ntl) {
      arz[rf][0][ntl] = vzero; arz[rf][1][ntl] = vzero;
      axn[rf][ntl] = vzero; ahn[rf][ntl] = vzero;
    }

  // stage the 12 KiB B-slice for weight-kt ktW into LDS buffer `buf`
  auto stage = [&](const bf16* Wh, const bf16* Wl2, int ktW, int buf) {
#pragma unroll
    for (int r = 0; r < 3; ++r) {
      int u = r * 256 + tid;     // 16B-unit index in [0,768)
      int tl2 = u >> 6;          // tile 0..11 = (g*2+ntl)*2+hl
      int ui = u & 63;
      int hl = tl2 & 1;
      int gn = tl2 >> 1;
      int g = gn >> 1, ntl = gn & 1;
      int ntg = g * 32 + (cw >> 4) + ntl;
      const bf16* src = (hl ? Wl2 : Wh) + ((size_t)(ktW * NT + ntg) * 64 + ui) * 8;
      *(bf16x8*)(&Bl[buf][tl2][ui * 8]) = ldf(src);
    }
  };
  // one kt of MFMA work from LDS buffer `buf`; n-gate accumulates into `an`
  auto compute = [&](const bf16* Ah, const bf16* Al, int lda, int ktA, int buf,
                     f32x4 (&an)[2][2]) {
    bf16x8 a[2][2];
#pragma unroll
    for (int rf = 0; rf < 2; ++rf) {
      const size_t ao = (size_t)(m0 + rf * 16 + lr) * lda + ktA * 32 + kq;
      a[rf][0] = ldf(Ah + ao);
      a[rf][1] = ldf(Al + ao);
    }
#pragma unroll
    for (int g = 0; g < 3; ++g)
#pragma unroll
      for (int ntl = 0; ntl < 2; ++ntl) {
        int tl2 = (g * 2 + ntl) * 2;
        bf16x8 bh  = *(const bf16x8*)(&Bl[buf][tl2][l * 8]);
        bf16x8 blo = *(const bf16x8*)(&Bl[buf][tl2 + 1][l * 8]);
#pragma unroll
        for (int rf = 0; rf < 2; ++rf) {
          if (g < 2)
            arz[rf][g][ntl] = mf(a[rf][0], blo, mf(a[rf][1], bh,
                                 mf(a[rf][0], bh, arz[rf][g][ntl])));
          else
            an[rf][ntl] = mf(a[rf][0], blo, mf(a[rf][1], bh,
                             mf(a[rf][0], bh, an[rf][ntl])));
        }
      }
  };

  // ---- pass 1: xg over KT1 kts (A = A1)
  stage(W1h, W1l, 0, 0);
  __syncthreads();
  for (int kt = 0; kt < KT1; ++kt) {
    const int buf = kt & 1;
    if (kt + 1 < KT1) stage(W1h, W1l, kt + 1, buf ^ 1);
    else if (!zero_h) stage(W2h, W2l, 0, buf ^ 1);
    compute(A1h, A1l, lda1, kt, buf, axn);
    __syncthreads();
  }
  // ---- pass 2: gh over 16 kts (A = h_prev)
  if (!zero_h) {
    for (int kt = 0; kt < 16; ++kt) {
      const int buf = (KT1 + kt) & 1;
      if (kt + 1 < 16) stage(W2h, W2l, kt + 1, buf ^ 1);
      compute(HPh, HPl, HH, kt, buf, ahn);
      __syncthreads();
    }
  }

  // ---- epilogue: gates + h update; h_prev = hi+lo reconstruction
#pragma unroll
  for (int ntl = 0; ntl < 2; ++ntl) {
    const int col = cw + ntl * 16 + lr;
    const float bx0 = b1[col], bx1 = b1[col + HH], bx2 = b1[col + 2 * HH];
    const float bh0 = b2[col], bh1 = b2[col + HH], bh2 = b2[col + 2 * HH];
#pragma unroll
    for (int rf = 0; rf < 2; ++rf)
#pragma unroll
      for (int i = 0; i < 4; ++i) {
        const int row = m0 + rf * 16 + lq * 4 + i;
        const float rr = sigf(arz[rf][0][ntl][i] + bx0 + bh0);
        const float zz = sigf(arz[rf][1][ntl][i] + bx1 + bh1);
        const float nn = tanhf(axn[rf][ntl][i] + bx2 + rr * (ahn[rf][ntl][i] + bh2));
        float hp = 0.f;
        const size_t hidx = (size_t)row * HH + col;
        if (!zero_h)
          hp = __bfloat162float(HPh[hidx]) + __bfloat162float(HPl[hidx]);
        const float hn = (1.f - zz) * nn + zz * hp;
        bf16 sh, sl;
        split2(hn, sh, sl);
        HOh[hidx] = sh;
        HOl[hidx] = sl;
      }
  }
}

// ---------------------------------------------------------------------------
// Output projection, last timestep only (fp32 VALU):
// o = relu(h1) @ W_out^T + b_out + res; res <- o; d_out[:,d,:] <- o (fp32);
// token slot 13+d <- split-bf16(o).  h1 comes in as hi/lo bf16.
// ---------------------------------------------------------------------------
__global__ __launch_bounds__(256) void out_v(
    const bf16* __restrict__ h1h, const bf16* __restrict__ h1l,
    const float* __restrict__ Wo,
    const float* __restrict__ bo,
    float* __restrict__ res,
    bf16* __restrict__ yh, bf16* __restrict__ yl,
    float* __restrict__ outp,
    int d)
{
  int idx = blockIdx.x * 256 + threadIdx.x;
  if (idx >= BB * YY) return;
  int col = idx % YY, row = idx / YY;
  const bf16* hrh = h1h + (size_t)row * HH;
  const bf16* hrl = h1l + (size_t)row * HH;
  const float* wr = Wo + (size_t)col * HH;
  float acc = 0.f;
#pragma unroll 2
  for (int k = 0; k < HH; k += 8) {
    bf16x8 hh = ldf(hrh + k);
    bf16x8 hl = ldf(hrl + k);
    f4 w0 = *(const f4*)&wr[k];
    f4 w1 = *(const f4*)&wr[k + 4];
#pragma unroll
    for (int j = 0; j < 4; ++j) {
      float hv0 = (float)hh[j] + (float)hl[j];
      float hv1 = (float)hh[j + 4] + (float)hl[j + 4];
      acc = fmaf(fmaxf(hv0, 0.f), w0[j], acc);
      acc = fmaf(fmaxf(hv1, 0.f), w1[j], acc);
    }
  }
  float o = acc + bo[col] + res[idx];
  res[idx] = o;
  outp[((size_t)row * DS + d) * YY + col] = o;
  bf16 sh, sl;
  split2(o, sh, sl);
  yh[(size_t)row * YP + col] = sh;
  yl[(size_t)row * YP + col] = sl;
}

extern "C" void kernel_launch(void* const* d_in, const int* in_sizes, int n_in,
                              void* d_out, int out_size, void* d_ws, size_t ws_size,
                              hipStream_t stream)
{
  // role mapping insurance (dict-order signature, greedy fallback)
  static const int sig_dict[11] = {2501632, 288768, 786432, 1536, 1536,
                                   786432, 786432, 1536, 1536, 96256, 188};
  int map[11];
  bool dict_ok = (n_in == 11);
  if (dict_ok)
    for (int r = 0; r < 11; ++r)
      if (in_sizes[r] != sig_dict[r]) { dict_ok = false; break; }
  if (dict_ok) { for (int r = 0; r < 11; ++r) map[r] = r; }
  else {
    bool used[16] = {};
    for (int r = 0; r < 11; ++r) {
      map[r] = r < n_in ? r : 0;
      for (int i = 0; i < n_in && i < 16; ++i)
        if (!used[i] && in_sizes[i] == sig_dict[r]) { map[r] = i; used[i] = true; break; }
    }
  }
  const float* x     = (const float*)d_in[map[0]];
  const float* W_ih0 = (const float*)d_in[map[1]];
  const float* W_hh0 = (const float*)d_in[map[2]];
  const float* b_ih0 = (const float*)d_in[map[3]];
  const float* b_hh0 = (const float*)d_in[map[4]];
  const float* W_ih1 = (const float*)d_in[map[5]];
  const float* W_hh1 = (const float*)d_in[map[6]];
  const float* b_ih1 = (const float*)d_in[map[7]];
  const float* b_hh1 = (const float*)d_in[map[8]];
  const float* W_out = (const float*)d_in[map[9]];
  const float* b_out = (const float*)d_in[map[10]];
  float* outp = (float*)d_out;

  // Schedule selection: skew-1 (25 phases, 13 h-slots, ~136 MB) if workspace
  // allows, else the proven skew-2 (37 phases, 7 slots, ~88 MB). ws_size is
  // fixed per-harness, so every call takes the same path (graph-safe).
  const int S    = (ws_size >= (size_t)160 << 20) ? 13 : 7;
  const int SKEW = (S == 13) ? 1 : 2;
  const int NPH  = 12 * SKEW + 13;

  char* p = (char*)d_ws;
  auto alloc = [&](size_t bytes) { char* q = p; p += (bytes + 255) & ~(size_t)255; return q; };
  bf16* tokh = (bf16*)alloc((size_t)26 * BB * YP * 2);
  bf16* tokl = (bf16*)alloc((size_t)26 * BB * YP * 2);
  bf16* W0h  = (bf16*)alloc((size_t)GG * YP * 2);
  bf16* W0l  = (bf16*)alloc((size_t)GG * YP * 2);
  bf16* Wh0h = (bf16*)alloc((size_t)GG * HH * 2);
  bf16* Wh0l = (bf16*)alloc((size_t)GG * HH * 2);
  bf16* Wi1h = (bf16*)alloc((size_t)GG * HH * 2);
  bf16* Wi1l = (bf16*)alloc((size_t)GG * HH * 2);
  bf16* Wh1h = (bf16*)alloc((size_t)GG * HH * 2);
  bf16* Wh1l = (bf16*)alloc((size_t)GG * HH * 2);
  bf16* h0h = (bf16*)alloc((size_t)2 * S * BB * HH * 2);  // parity x slot
  bf16* h0l = (bf16*)alloc((size_t)2 * S * BB * HH * 2);
  bf16* h1h = (bf16*)alloc((size_t)2 * S * BB * HH * 2);
  bf16* h1l = (bf16*)alloc((size_t)2 * S * BB * HH * 2);
  float* res = (float*)alloc((size_t)BB * YY * 4);

  k_setup<<<(26 * BB * YP + 255) / 256, 256, 0, stream>>>(x, tokh, tokl, res);
  k_swz2<<<NT * (YP / 32) * 64 / 256, 256, 0, stream>>>(W_ih0, W0h, W0l, GG, YY);
  k_swz2<<<NT * (HH / 32) * 64 / 256, 256, 0, stream>>>(W_hh0, Wh0h, Wh0l, GG, HH);
  k_swz2<<<NT * (HH / 32) * 64 / 256, 256, 0, stream>>>(W_ih1, Wi1h, Wi1l, GG, HH);
  k_swz2<<<NT * (HH / 32) * 64 / 256, 256, 0, stream>>>(W_hh1, Wh1h, Wh1l, GG, HH);

  // Diagonal wavefront: phase(d,t) = t + SKEW*d. Cells in phase p read
  // h-parity (p-1)&1, write p&1; slot = d % S.
  for (int phs = 0; phs < NPH; ++phs) {
    GruPhase P0{}, P1{};
    const int pprev = (phs + 1) & 1, pcur = phs & 1;
    int C = 0;
    for (int d = 0; d < DS; ++d) {
      int t = phs - SKEW * d;
      if (t < 0 || t > 12) continue;
      int c = C++;
      P0.a1off[c] = (unsigned)((d + t) * BB * YP);          // token slot d+t
      P0.hoff[c]  = (unsigned)((pprev * S + d % S) * BB * HH);
      P0.ooff[c]  = (unsigned)((pcur * S + d % S) * BB * HH);
      if (t == 0) P0.zmask |= 1 << c;
      P1.a1off[c] = P0.ooff[c];   // L1 input = L0 output of this phase
      P1.hoff[c]  = P0.hoff[c];
      P1.ooff[c]  = P0.ooff[c];
    }
    P0.ncells = P1.ncells = C;
    P1.zmask = P0.zmask;
    const dim3 grid(16, C * 8);   // x=colgroups (XCD locality), y=row-tiles
    gru2<YP / 32><<<grid, 256, 0, stream>>>(tokh, tokl, YP, W0h, W0l, b_ih0,
                                            h0h, h0l, Wh0h, Wh0l, b_hh0,
                                            h0h, h0l, P0);
    gru2<HH / 32><<<grid, 256, 0, stream>>>(h0h, h0l, HH, Wi1h, Wi1l, b_ih1,
                                            h1h, h1l, Wh1h, Wh1l, b_hh1,
                                            h1h, h1l, P1);
    // decode step d finishes at phase 12 + SKEW*d: project + feed token 13+d
    if (phs >= 12 && (phs - 12) % SKEW == 0) {
      const int d = (phs - 12) / SKEW;
      const size_t hoff = (size_t)(pcur * S + d % S) * BB * HH;
      out_v<<<(BB * YY + 255) / 256, 256, 0, stream>>>(
          h1h + hoff, h1l + hoff, W_out, b_out, res,
          tokh + (size_t)(13 + d) * BB * YP, tokl + (size_t)(13 + d) * BB * YP,
          outp, d);
    }
  }
}